// Round 11
// baseline (98.270 us; speedup 1.0000x reference)
//
#include <hip/hip_runtime.h>

// GaussianDynamics recurrent cell as a parallel affine scan.
// x_t = S_t x_{t-1} + o_t,  S_t = I + (A - xic_t C) dt,  o_t = xic_t dy_t
// out_t = C x_{t-1} dt  (pre-update state)
//
// R11 = R10 (97.7us) + split waitcnt:
//  - vmcnt(2) drains only the 4 global_load_lds (issued first); the 2 dy
//    dwordx4 stay in flight and their latency hides under the S-compose
//    (which needs only LDS data). Compiler's register-dep waitcnt covers dy.
//  - sched_barrier(0) between gload_lds and dy loads pins issue order so
//    vmcnt(2) provably drains the right ops.
//  - Compose reordered: S for all 4 steps (LDS-only) first, then o + M-chain.

constexpr int BATCH = 16384;
constexpr int TLEN  = 1000;
constexpr int TPB   = 256;
constexpr int SPT   = 4;     // TPB*SPT = 1024 >= TLEN; 1000/4=250 full chunks

typedef float vfloat4 __attribute__((ext_vector_type(4)));
typedef float vfloat2 __attribute__((ext_vector_type(2)));

template <int CTRL, int ROWMASK>
__device__ __forceinline__ float dppf(float oldv, float srcv) {
    return __int_as_float(__builtin_amdgcn_update_dpp(
        __float_as_int(oldv), __float_as_int(srcv), CTRL, ROWMASK, 0xf, false));
}

__global__ __launch_bounds__(TPB, 8) void gd_scan_kernel(
    const float* __restrict__ xicovs,  // [B,T,2,2]
    const float* __restrict__ dyv,     // [B,T,2]
    const float* __restrict__ cA,      // [2,2]
    const float* __restrict__ Cm,      // [2,2]
    const float* __restrict__ x0,      // [B,2]
    const float* __restrict__ dtp,     // [1]
    float* __restrict__ out)           // [B,T,2] then [B,2]
{
    __shared__ vfloat4 s_xc[1024];        // AoS granules (16B = one timestep)
    __shared__ float wsum[TPB / 64][6];

    const int b    = blockIdx.x;
    const int tid  = threadIdx.x;
    const int lane = tid & 63;
    const int wv   = tid >> 6;

    const int t0  = tid * SPT;
    const int t0m = (t0 <= TLEN - SPT) ? t0 : (TLEN - SPT);
    const bool valid = (t0 < TLEN);       // threads 250..255 idle (identity)

    const float* rowx = xicovs + (size_t)b * TLEN * 4;

    // ---- per-wave self-staging: 4x global_load_lds(16B) into own quarter,
    //      XOR-involution pre-swizzled source (G21) ----
#pragma unroll
    for (int k = 0; k < 4; ++k) {
        const int pw = k * 64 + lane;
        const int gw = pw ^ ((pw >> 3) & 7);
        int g = 256 * wv + gw;
        if (g > TLEN - 1) g = TLEN - 1;
        __builtin_amdgcn_global_load_lds(
            (const __attribute__((address_space(1))) void*)(rowx + (size_t)g * 4),
            (__attribute__((address_space(3))) void*)&s_xc[wv * 256 + k * 64],
            16, 0, 0);
    }

    // pin issue order: dy loads must not be scheduled before the gload_lds,
    // or vmcnt(2) below would under-drain.
    __builtin_amdgcn_sched_barrier(0);

    // ---- dy: per-thread contiguous 32B (2x dwordx4), stays in flight ----
    const vfloat4* gd4 = reinterpret_cast<const vfloat4*>(dyv + (size_t)b * TLEN * 2);
    const vfloat4 dA = gd4[(t0m >> 1)];
    const vfloat4 dB = gd4[(t0m >> 1) + 1];

    // ---- uniform params as row/col pairs (scalar loads, lgkmcnt path) ----
    const float dts = dtp[0];
    const vfloat2 CdColA = {Cm[0] * dts, Cm[2] * dts};     // (Cd00, Cd10)
    const vfloat2 CdColB = {Cm[1] * dts, Cm[3] * dts};     // (Cd01, Cd11)
    const vfloat2 nCdRow0 = {-Cm[0] * dts, -Cm[1] * dts};  // -(Cd00, Cd01)
    const vfloat2 nCdRow1 = {-Cm[2] * dts, -Cm[3] * dts};  // -(Cd10, Cd11)
    const vfloat2 AdRow0 = {1.f + cA[0] * dts, cA[1] * dts};
    const vfloat2 AdRow1 = {cA[2] * dts, 1.f + cA[3] * dts};
    const float xa = x0[2 * b], xb = x0[2 * b + 1];

    // ---- drain ONLY the 4 gload_lds; dy (last 2 issued) keeps flying ----
    asm volatile("s_waitcnt vmcnt(2)" ::: "memory");

    // ---- read own 4 timesteps: swizzled ds_read_b128 ----
    vfloat4 xc[SPT];
#pragma unroll
    for (int s = 0; s < SPT; ++s) {
        const int gw  = 4 * lane + s;
        const int pos = gw ^ ((gw >> 3) & 7);
        xc[s] = s_xc[wv * 256 + pos];
    }

    // ---- S-matrices first: LDS-only inputs, runs while dy is in flight ----
    vfloat2 Sa[SPT], Sb[SPT];
#pragma unroll
    for (int s = 0; s < SPT; ++s) {
        const vfloat4 xi = xc[s];
        Sa[s] = AdRow0 + xi.x * nCdRow0 + xi.y * nCdRow1;  // (S00,S01)
        Sb[s] = AdRow1 + xi.z * nCdRow0 + xi.w * nCdRow1;  // (S10,S11)
    }

    // ---- o-vectors (first dy use -> compiler waits here) + M,c chain ----
    const float dy0s[SPT] = {dA.x, dA.z, dB.x, dB.z};
    const float dy1s[SPT] = {dA.y, dA.w, dB.y, dB.w};

    vfloat2 ov[SPT];
    vfloat2 mA = {1.f, 0.f}, mB = {0.f, 1.f}, cc = {0.f, 0.f};
#pragma unroll
    for (int s = 0; s < SPT; ++s) {
        const vfloat4 xi = xc[s];
        const float o0 = xi.x * dy0s[s] + xi.y * dy1s[s];
        const float o1 = xi.z * dy0s[s] + xi.w * dy1s[s];
        ov[s] = vfloat2{o0, o1};
        const vfloat2 sa = Sa[s], sb = Sb[s];
        // M = S o M ; c = S c + o
        const vfloat2 nA = sa.x * mA + sa.y * mB;
        const vfloat2 nB = sb.x * mA + sb.y * mB;
        const float nc0 = sa.x * cc.x + sa.y * cc.y + o0;
        const float nc1 = sb.x * cc.x + sb.y * cc.y + o1;
        mA = nA; mB = nB; cc = vfloat2{nc0, nc1};
    }
    if (!valid) { mA = vfloat2{1.f, 0.f}; mB = vfloat2{0.f, 1.f}; cc = vfloat2{0.f, 0.f}; }

    // ---- wave-level inclusive scan via DPP + packed combine ----
#define SCAN_STEP(CTRL, RM)                                          \
    do {                                                             \
        vfloat2 smA, smB, scc;                                       \
        smA.x = dppf<CTRL, RM>(1.f, mA.x);                           \
        smA.y = dppf<CTRL, RM>(0.f, mA.y);                           \
        smB.x = dppf<CTRL, RM>(0.f, mB.x);                           \
        smB.y = dppf<CTRL, RM>(1.f, mB.y);                           \
        scc.x = dppf<CTRL, RM>(0.f, cc.x);                           \
        scc.y = dppf<CTRL, RM>(0.f, cc.y);                           \
        const vfloat2 nA = mA.x * smA + mA.y * smB;                  \
        const vfloat2 nB = mB.x * smA + mB.y * smB;                  \
        const float nc0 = mA.x * scc.x + mA.y * scc.y + cc.x;        \
        const float nc1 = mB.x * scc.x + mB.y * scc.y + cc.y;        \
        mA = nA; mB = nB; cc = vfloat2{nc0, nc1};                    \
    } while (0)

    SCAN_STEP(0x111, 0xf);  // row_shr:1
    SCAN_STEP(0x112, 0xf);  // row_shr:2
    SCAN_STEP(0x114, 0xf);  // row_shr:4
    SCAN_STEP(0x118, 0xf);  // row_shr:8
    SCAN_STEP(0x142, 0xa);  // row_bcast:15 -> rows 1,3
    SCAN_STEP(0x143, 0xc);  // row_bcast:31 -> rows 2,3
#undef SCAN_STEP

    // ---- inter-wave fixup ----
    if (lane == 63) {
        wsum[wv][0] = mA.x; wsum[wv][1] = mA.y;
        wsum[wv][2] = mB.x; wsum[wv][3] = mB.y;
        wsum[wv][4] = cc.x; wsum[wv][5] = cc.y;
    }
    __syncthreads();

    vfloat2 pA = {1.f, 0.f}, pB = {0.f, 1.f}, pc = {0.f, 0.f};
    for (int w = 0; w < wv; ++w) {
        const vfloat2 tA = {wsum[w][0], wsum[w][1]};
        const vfloat2 tB = {wsum[w][2], wsum[w][3]};
        const vfloat2 tc = {wsum[w][4], wsum[w][5]};
        const vfloat2 nA = tA.x * pA + tA.y * pB;   // P = T_w o P
        const vfloat2 nB = tB.x * pA + tB.y * pB;
        const float nc0 = tA.x * pc.x + tA.y * pc.y + tc.x;
        const float nc1 = tB.x * pc.x + tB.y * pc.y + tc.y;
        pA = nA; pB = nB; pc = vfloat2{nc0, nc1};
    }

    // ---- within-wave exclusive = inclusive of lane-1 ----
    vfloat2 eA, eB, ec;
    eA.x = __shfl_up(mA.x, 1); eA.y = __shfl_up(mA.y, 1);
    eB.x = __shfl_up(mB.x, 1); eB.y = __shfl_up(mB.y, 1);
    ec.x = __shfl_up(cc.x, 1); ec.y = __shfl_up(cc.y, 1);
    if (lane == 0) { eA = vfloat2{1.f, 0.f}; eB = vfloat2{0.f, 1.f}; ec = vfloat2{0.f, 0.f}; }

    // E = e o P
    const vfloat2 EA = eA.x * pA + eA.y * pB;
    const vfloat2 EB = eB.x * pA + eB.y * pB;
    const float Ec0 = eA.x * pc.x + eA.y * pc.y + ec.x;
    const float Ec1 = eB.x * pc.x + eB.y * pc.y + ec.y;

    // start state for this chunk: x_{t0-1} = E(x0)
    float xq0 = EA.x * xa + EA.y * xb + Ec0;
    float xq1 = EB.x * xa + EB.y * xb + Ec1;

    // ---- replay chunk, emit outputs (Cd folded; pair = (o0,o1) adjacent) ----
    vfloat2 op[SPT];
#pragma unroll
    for (int s = 0; s < SPT; ++s) {
        op[s] = xq0 * CdColA + xq1 * CdColB;
        const float nx0 = Sa[s].x * xq0 + Sa[s].y * xq1 + ov[s].x;
        const float nx1 = Sb[s].x * xq0 + Sb[s].y * xq1 + ov[s].y;
        xq0 = nx0; xq1 = nx1;
    }

    if (valid) {
        float* ob = out + (size_t)b * TLEN * 2 + (size_t)t0 * 2;
        vfloat4 w0 = {op[0].x, op[0].y, op[1].x, op[1].y};
        vfloat4 w1 = {op[2].x, op[2].y, op[3].x, op[3].y};
        __builtin_nontemporal_store(w0, reinterpret_cast<vfloat4*>(ob));
        __builtin_nontemporal_store(w1, reinterpret_cast<vfloat4*>(ob) + 1);
    }
    if (t0 == TLEN - SPT) {   // owns steps 996..999 -> final state
        vfloat2 xf = {xq0, xq1};
        __builtin_nontemporal_store(
            xf, reinterpret_cast<vfloat2*>(out + (size_t)BATCH * TLEN * 2 + 2 * b));
    }
}

extern "C" void kernel_launch(void* const* d_in, const int* in_sizes, int n_in,
                              void* d_out, int out_size, void* d_ws, size_t ws_size,
                              hipStream_t stream) {
    const float* xicovs = (const float*)d_in[0];
    const float* dyv    = (const float*)d_in[1];
    const float* cA     = (const float*)d_in[2];
    const float* Cm     = (const float*)d_in[3];
    const float* x0     = (const float*)d_in[4];
    const float* dtp    = (const float*)d_in[5];
    float* out = (float*)d_out;

    gd_scan_kernel<<<BATCH, TPB, 0, stream>>>(xicovs, dyv, cA, Cm, x0, dtp, out);
}